// Round 11
// baseline (237.185 us; speedup 1.0000x reference)
//
#include <hip/hip_runtime.h>
#include <hip/hip_bf16.h>
#include <math.h>

#define NN 50000
#define NE 800000
#define NBK 196          // buckets = (NN+255)/256, bucket = dst>>8
#define CHUNK 8192
#define NCH ((NE + CHUNK - 1) / CHUNK)   // 98 chunks (= runs per bucket)
#define RCAP 96          // capacity per (bucket,chunk) run; mean 41.8, +8 sigma
#define APITCH 136       // padded bf16 row pitch for gemm1 A-tile
#define G1BLOCKS ((NN + 63) / 64)        // 782
#define OSLCAP 2560      // per-block (64-node) edge list cap; mean 1152, +42 sigma

typedef short bf16x8 __attribute__((ext_vector_type(8)));
typedef float f32x4  __attribute__((ext_vector_type(4)));
typedef float f32x2  __attribute__((ext_vector_type(2)));

// ---------- bf16 helpers ----------
__device__ __forceinline__ unsigned short f2bf(float f) {
    union { float f; unsigned int i; } v; v.f = f;
    unsigned int x = v.i;
    unsigned int r = (x >> 16) & 1u;          // round-to-nearest-even
    x += 0x7fffu + r;
    return (unsigned short)(x >> 16);
}
__device__ __forceinline__ f32x2 up2(unsigned int u) {
    union { unsigned int i; float f; } x, y;
    x.i = u << 16; y.i = u & 0xffff0000u;
    return (f32x2){x.f, y.f};
}

// ---------- MERGED: edge binning (fixed slots, blocks 0..NCH-1) || layer-1 MFMA GEMM ----------
__global__ __launch_bounds__(256) void k_bin_gemm1(
    const int* __restrict__ ei,
    unsigned int* __restrict__ packed, int* __restrict__ cnts,
    const float* __restrict__ x, const float* __restrict__ W1,
    const float* __restrict__ aS, const float* __restrict__ aD,
    unsigned short* __restrict__ h1, float* __restrict__ as1,
    float* __restrict__ ad1)
{
    __shared__ union {
        int h[NBK];
        unsigned short alds[64 * APITCH];          // 34816 B
    } sm;
    int t = threadIdx.x;

    if (blockIdx.x < NCH) {
        // -------- bin: single pass, direct placement into fixed runs --------
        int* h = sm.h;
        if (t < NBK) h[t] = 0;
        __syncthreads();
        int cb = blockIdx.x * CHUNK;
#pragma unroll
        for (int k = 0; k < CHUNK / 256; k++) {
            int i = cb + k * 256 + t;
            if (i < NE) {
                int s = ei[i], d = ei[NE + i];
                int b = d >> 8;
                int r = atomicAdd(&h[b], 1);
                if (r < RCAP)
                    packed[((size_t)b * NCH + blockIdx.x) * RCAP + r] =
                        (unsigned int)s | ((unsigned int)(d & 255) << 16);
            }
        }
        __syncthreads();
        if (t < NBK) cnts[t * NCH + blockIdx.x] = (h[t] < RCAP) ? h[t] : RCAP;
        return;
    }

    // -------- gemm1 body (MFMA, self-swizzled W1 fragments) --------
    unsigned short* Alds = sm.alds;
    int w = t >> 6, l = t & 63;
    int rowbase = (blockIdx.x - NCH) * 64;

    {   // stage A: 64x128 fp32 -> bf16 LDS
        const float4* xg = (const float4*)(x + (size_t)rowbase * 128);
#pragma unroll
        for (int i = 0; i < 8; i++) {
            int idx = t + 256 * i;
            int r = idx >> 5, c = (idx & 31) * 4;
            float4 v = make_float4(0.f, 0.f, 0.f, 0.f);
            if (rowbase + r < NN) v = xg[idx];
            unsigned int p0 = (unsigned int)f2bf(v.x) | ((unsigned int)f2bf(v.y) << 16);
            unsigned int p1 = (unsigned int)f2bf(v.z) | ((unsigned int)f2bf(v.w) << 16);
            *(uint2*)&Alds[r * APITCH + c] = make_uint2(p0, p1);
        }
    }

    union BU { uint4 u; bf16x8 v; };
    BU b[2][4];
    {   // self-swizzle W1 -> B fragments (W1 is L2-resident across blocks)
        int n_lo = l & 15, k0b = (l >> 4) * 8;
#pragma unroll
        for (int j = 0; j < 2; j++) {
            int n = (2 * w + j) * 16 + n_lo;
#pragma unroll
            for (int kc = 0; kc < 4; kc++) {
                int k0 = kc * 32 + k0b;
                unsigned int p[4];
#pragma unroll
                for (int jj = 0; jj < 4; jj++) {
                    float v0 = W1[(k0 + 2 * jj) * 128 + n];
                    float v1 = W1[(k0 + 2 * jj + 1) * 128 + n];
                    p[jj] = (unsigned int)f2bf(v0) | ((unsigned int)f2bf(v1) << 16);
                }
                b[j][kc].u = make_uint4(p[0], p[1], p[2], p[3]);
            }
        }
    }
    __syncthreads();

    f32x4 acc[4][2];
#pragma unroll
    for (int mt = 0; mt < 4; mt++)
#pragma unroll
        for (int j = 0; j < 2; j++) acc[mt][j] = (f32x4){0.f, 0.f, 0.f, 0.f};

    int mrow = l & 15, quad = l >> 4;
#pragma unroll
    for (int kc = 0; kc < 4; kc++) {
#pragma unroll
        for (int mt = 0; mt < 4; mt++) {
            bf16x8 a = *(const bf16x8*)&Alds[(mt * 16 + mrow) * APITCH + kc * 32 + quad * 8];
            acc[mt][0] = __builtin_amdgcn_mfma_f32_16x16x32_bf16(a, b[0][kc].v, acc[mt][0], 0, 0, 0);
            acc[mt][1] = __builtin_amdgcn_mfma_f32_16x16x32_bf16(a, b[1][kc].v, acc[mt][1], 0, 0, 0);
        }
    }

#pragma unroll
    for (int j = 0; j < 2; j++) {
        int head = 2 * w + j;
        float aSv = aS[head * 16 + mrow];
        float aDv = aD[head * 16 + mrow];
#pragma unroll
        for (int mt = 0; mt < 4; mt++) {
#pragma unroll
            for (int reg = 0; reg < 4; reg++) {
                float s = acc[mt][j][reg] * aSv;
                float d = acc[mt][j][reg] * aDv;
                s += __shfl_xor(s, 1); s += __shfl_xor(s, 2);
                s += __shfl_xor(s, 4); s += __shfl_xor(s, 8);
                d += __shfl_xor(d, 1); d += __shfl_xor(d, 2);
                d += __shfl_xor(d, 4); d += __shfl_xor(d, 8);
                if (mrow == 0) {
                    int grow = rowbase + mt * 16 + quad * 4 + reg;
                    if (grow < NN) {
                        as1[grow * 8 + head] = s;
                        ad1[grow * 8 + head] = d;
                    }
                }
            }
        }
    }

    __syncthreads();   // A reads done; reuse Alds for C transpose
#pragma unroll
    for (int mt = 0; mt < 4; mt++)
#pragma unroll
        for (int j = 0; j < 2; j++) {
            int col = w * 32 + j * 16 + mrow;
#pragma unroll
            for (int reg = 0; reg < 4; reg++) {
                int r = mt * 16 + quad * 4 + reg;
                Alds[r * APITCH + col] = f2bf(acc[mt][j][reg]);
            }
        }
    __syncthreads();
    uint4* hg = (uint4*)h1;
#pragma unroll
    for (int i = 0; i < 4; i++) {
        int idx = t + 256 * i;
        int r = idx >> 4, ci = idx & 15;
        if (rowbase + r < NN)
            hg[(size_t)(rowbase + r) * 16 + ci] = *(const uint4*)&Alds[r * APITCH + ci * 8];
    }
}

// ---------- FUSED rank + layer-1 aggregation: block = (bucket, quarter of 64 nodes) ----------
__global__ __launch_bounds__(256) void k_final_agg1(
    const unsigned int* __restrict__ packed, const int* __restrict__ cnts,
    const float* __restrict__ as1, const float* __restrict__ ad1,
    const unsigned short* __restrict__ h1, const float* __restrict__ b1,
    unsigned short* __restrict__ h2)
{
    __shared__ int rcnt[NCH];
    __shared__ int osl[OSLCAP];
    __shared__ int cnt[64], pre[64], cur[64];
    int t = threadIdx.x;
    int B = blockIdx.x >> 2, q = blockIdx.x & 3;
    int nbase = B * 256 + q * 64;
    if (t < NCH) rcnt[t] = cnts[B * NCH + t];
    if (t < 64) cnt[t] = 0;
    __syncthreads();

    int wv = t >> 6, ln = t & 63;
    const size_t pbase = (size_t)B * NCH * RCAP;

    // pass 1: histogram of this block's 64 nodes
    for (int c = wv; c < NCH; c += 4) {
        int m = rcnt[c];
        for (int i = ln; i < m; i += 64) {
            unsigned int e = packed[pbase + (size_t)c * RCAP + i];
            int dl = (e >> 16) & 255;
            if ((dl >> 6) == q) atomicAdd(&cnt[dl & 63], 1);
        }
    }
    __syncthreads();
    if (t == 0) {              // tiny serial scan of 64 (+1 self-slot each)
        int run = 0;
        for (int k = 0; k < 64; k++) { pre[k] = run; cur[k] = run; run += cnt[k] + 1; }
    }
    __syncthreads();
    // self-loops at segment ends
    if (t < 64) {
        int node = nbase + t;
        if (node < NN) osl[pre[t] + cnt[t]] = node;
    }
    // pass 2: rank-scatter matching edges
    for (int c = wv; c < NCH; c += 4) {
        int m = rcnt[c];
        for (int i = ln; i < m; i += 64) {
            unsigned int e = packed[pbase + (size_t)c * RCAP + i];
            int dl = (e >> 16) & 255;
            if ((dl >> 6) == q) {
                int r = atomicAdd(&cur[dl & 63], 1);
                if (r < OSLCAP) osl[r] = (int)(e & 0xffffu);
            }
        }
    }
    __syncthreads();

    // aggregation: wave wv handles nodes k = wv + 4*i (interleaved for balance)
    const uint4* h1u4 = (const uint4*)h1;
    int li = ln & 7, jg = ln >> 3;   // li = head, 32B/lane of the h1 row
    for (int i = 0; i < 16; i++) {
        int k = wv + 4 * i;
        int node = nbase + k;
        if (node >= NN) continue;
        int start = pre[k], cnt2 = cnt[k] + 1;
        float adv = ad1[node * 8 + li];

        f32x2 acc[8];
#pragma unroll
        for (int z = 0; z < 8; z++) acc[z] = (f32x2){0.f, 0.f};
        float dsum = 0.f;

        for (int base = 0; base < cnt2; base += 16) {
#pragma unroll
            for (int u = 0; u < 2; u++) {
                int j = base + u * 8 + jg;
                if (j < cnt2) {
                    int s = osl[start + j];
                    float e = as1[s * 8 + li] + adv;
                    e = (e > 0.f) ? e : 0.2f * e;
                    float wgt = __expf(e);
                    uint4 ha = h1u4[(size_t)s * 16 + 2 * li];
                    uint4 hb = h1u4[(size_t)s * 16 + 2 * li + 1];
                    f32x2 w2 = (f32x2){wgt, wgt};
                    acc[0] += w2 * up2(ha.x); acc[1] += w2 * up2(ha.y);
                    acc[2] += w2 * up2(ha.z); acc[3] += w2 * up2(ha.w);
                    acc[4] += w2 * up2(hb.x); acc[5] += w2 * up2(hb.y);
                    acc[6] += w2 * up2(hb.z); acc[7] += w2 * up2(hb.w);
                    dsum += wgt;
                }
            }
        }
#pragma unroll
        for (int z = 0; z < 8; z++) {
            acc[z].x += __shfl_xor(acc[z].x, 8);  acc[z].y += __shfl_xor(acc[z].y, 8);
            acc[z].x += __shfl_xor(acc[z].x, 16); acc[z].y += __shfl_xor(acc[z].y, 16);
            acc[z].x += __shfl_xor(acc[z].x, 32); acc[z].y += __shfl_xor(acc[z].y, 32);
        }
        dsum += __shfl_xor(dsum, 8);
        dsum += __shfl_xor(dsum, 16);
        dsum += __shfl_xor(dsum, 32);

        if (jg == 0) {
            float inv = 1.0f / dsum;
            int c0 = li * 16;
            float v[16];
#pragma unroll
            for (int z = 0; z < 8; z++) {
                float v0 = acc[z].x * inv + b1[c0 + 2 * z];
                float v1 = acc[z].y * inv + b1[c0 + 2 * z + 1];
                v[2 * z]     = (v0 > 0.f) ? v0 : (__expf(v0) - 1.0f);   // ELU
                v[2 * z + 1] = (v1 > 0.f) ? v1 : (__expf(v1) - 1.0f);
            }
            uint4 o0, o1;
            o0.x = (unsigned int)f2bf(v[0])  | ((unsigned int)f2bf(v[1])  << 16);
            o0.y = (unsigned int)f2bf(v[2])  | ((unsigned int)f2bf(v[3])  << 16);
            o0.z = (unsigned int)f2bf(v[4])  | ((unsigned int)f2bf(v[5])  << 16);
            o0.w = (unsigned int)f2bf(v[6])  | ((unsigned int)f2bf(v[7])  << 16);
            o1.x = (unsigned int)f2bf(v[8])  | ((unsigned int)f2bf(v[9])  << 16);
            o1.y = (unsigned int)f2bf(v[10]) | ((unsigned int)f2bf(v[11]) << 16);
            o1.z = (unsigned int)f2bf(v[12]) | ((unsigned int)f2bf(v[13]) << 16);
            o1.w = (unsigned int)f2bf(v[14]) | ((unsigned int)f2bf(v[15]) << 16);
            ((uint4*)h2)[(size_t)node * 16 + 2 * li] = o0;
            ((uint4*)h2)[(size_t)node * 16 + 2 * li + 1] = o1;
        }
    }
}

// ---------- Layer 2 GEMM via MFMA (self-swizzled W2), no LDS ----------
__global__ __launch_bounds__(256) void k_gemm2(
    const unsigned short* __restrict__ h2,   // [NN,128] bf16
    const float* __restrict__ W2,            // [128,16] fp32
    const float* __restrict__ aS2, const float* __restrict__ aD2,
    float* __restrict__ g2, float* __restrict__ as2, float* __restrict__ ad2)
{
    int t = threadIdx.x;
    int w = t >> 6, l = t & 63;
    int rowbase = blockIdx.x * 64 + w * 16;
    int arow = l & 15, quad = l >> 4;
    int row = rowbase + arow; if (row >= NN) row = NN - 1;   // clamp (discarded on store)

    union BU { uint4 u; bf16x8 v; };
    BU bfr[4];
    {
        int n = l & 15, k0b = (l >> 4) * 8;
#pragma unroll
        for (int kc = 0; kc < 4; kc++) {
            int k0 = kc * 32 + k0b;
            unsigned int p[4];
#pragma unroll
            for (int jj = 0; jj < 4; jj++) {
                float v0 = W2[(k0 + 2 * jj) * 16 + n];
                float v1 = W2[(k0 + 2 * jj + 1) * 16 + n];
                p[jj] = (unsigned int)f2bf(v0) | ((unsigned int)f2bf(v1) << 16);
            }
            bfr[kc].u = make_uint4(p[0], p[1], p[2], p[3]);
        }
    }

    f32x4 acc = (f32x4){0.f, 0.f, 0.f, 0.f};
#pragma unroll
    for (int kc = 0; kc < 4; kc++) {
        bf16x8 a = *(const bf16x8*)&h2[(size_t)row * 128 + kc * 32 + quad * 8];
        acc = __builtin_amdgcn_mfma_f32_16x16x32_bf16(a, bfr[kc].v, acc, 0, 0, 0);
    }

    int col = l & 15;
    float aSv = aS2[col], aDv = aD2[col];
#pragma unroll
    for (int reg = 0; reg < 4; reg++) {
        int grow = rowbase + quad * 4 + reg;
        if (grow < NN) g2[(size_t)grow * 16 + col] = acc[reg];
        float s = acc[reg] * aSv;
        float d = acc[reg] * aDv;
        s += __shfl_xor(s, 1); s += __shfl_xor(s, 2);
        s += __shfl_xor(s, 4); s += __shfl_xor(s, 8);
        d += __shfl_xor(d, 1); d += __shfl_xor(d, 2);
        d += __shfl_xor(d, 4); d += __shfl_xor(d, 8);
        if (col == 0 && grow < NN) { as2[grow] = s; ad2[grow] = d; }
    }
}

// ---------- FUSED rank + layer-2 aggregation ----------
__global__ __launch_bounds__(256) void k_final_agg2(
    const unsigned int* __restrict__ packed, const int* __restrict__ cnts,
    const float* __restrict__ as2, const float* __restrict__ ad2,
    const float* __restrict__ g2, const float* __restrict__ b2,
    float* __restrict__ out)
{
    __shared__ int rcnt[NCH];
    __shared__ int osl[OSLCAP];
    __shared__ int cnt[64], pre[64], cur[64];
    int t = threadIdx.x;
    int B = blockIdx.x >> 2, q = blockIdx.x & 3;
    int nbase = B * 256 + q * 64;
    if (t < NCH) rcnt[t] = cnts[B * NCH + t];
    if (t < 64) cnt[t] = 0;
    __syncthreads();

    int wv = t >> 6, ln = t & 63;
    const size_t pbase = (size_t)B * NCH * RCAP;

    for (int c = wv; c < NCH; c += 4) {
        int m = rcnt[c];
        for (int i = ln; i < m; i += 64) {
            unsigned int e = packed[pbase + (size_t)c * RCAP + i];
            int dl = (e >> 16) & 255;
            if ((dl >> 6) == q) atomicAdd(&cnt[dl & 63], 1);
        }
    }
    __syncthreads();
    if (t == 0) {
        int run = 0;
        for (int k = 0; k < 64; k++) { pre[k] = run; cur[k] = run; run += cnt[k] + 1; }
    }
    __syncthreads();
    if (t < 64) {
        int node = nbase + t;
        if (node < NN) osl[pre[t] + cnt[t]] = node;
    }
    for (int c = wv; c < NCH; c += 4) {
        int m = rcnt[c];
        for (int i = ln; i < m; i += 64) {
            unsigned int e = packed[pbase + (size_t)c * RCAP + i];
            int dl = (e >> 16) & 255;
            if ((dl >> 6) == q) {
                int r = atomicAdd(&cur[dl & 63], 1);
                if (r < OSLCAP) osl[r] = (int)(e & 0xffffu);
            }
        }
    }
    __syncthreads();

    const float4* g2f4 = (const float4*)g2;
    int li4 = ln & 3, jgg = ln >> 2;   // 16 edge groups x 4 lanes (16B of g2 row each)
    for (int i = 0; i < 16; i++) {
        int k = wv + 4 * i;
        int node = nbase + k;
        if (node >= NN) continue;
        int start = pre[k], cnt2 = cnt[k] + 1;
        float adv = ad2[node];

        float a0 = 0.f, a1 = 0.f, a2 = 0.f, a3 = 0.f, dsum = 0.f;
        for (int base = 0; base < cnt2; base += 32) {
#pragma unroll
            for (int u = 0; u < 2; u++) {
                int j = base + u * 16 + jgg;
                if (j < cnt2) {
                    int s = osl[start + j];
                    float e = as2[s] + adv;
                    e = (e > 0.f) ? e : 0.2f * e;
                    float wgt = __expf(e);
                    float4 g = g2f4[(size_t)s * 4 + li4];
                    a0 += wgt * g.x; a1 += wgt * g.y; a2 += wgt * g.z; a3 += wgt * g.w;
                    if (li4 == 0) dsum += wgt;
                }
            }
        }
#pragma unroll
        for (int m = 4; m < 64; m <<= 1) {
            a0 += __shfl_xor(a0, m); a1 += __shfl_xor(a1, m);
            a2 += __shfl_xor(a2, m); a3 += __shfl_xor(a3, m);
            dsum += __shfl_xor(dsum, m);
        }
        dsum += __shfl_xor(dsum, 1);
        dsum += __shfl_xor(dsum, 2);   // broadcast denom to all li4

        if (jgg == 0) {
            float inv = 1.0f / dsum;
            const float4* b2f4 = (const float4*)b2;
            float4 bb = b2f4[li4];
            float4 o = make_float4(a0 * inv + bb.x, a1 * inv + bb.y,
                                   a2 * inv + bb.z, a3 * inv + bb.w);
            ((float4*)out)[(size_t)node * 4 + li4] = o;
        }
    }
}

// ---------- launch ----------
extern "C" void kernel_launch(void* const* d_in, const int* in_sizes, int n_in,
                              void* d_out, int out_size, void* d_ws, size_t ws_size,
                              hipStream_t stream) {
    const float* x   = (const float*)d_in[0];
    const int*   ei  = (const int*)d_in[1];
    const float* W1  = (const float*)d_in[2];
    const float* aS1 = (const float*)d_in[3];
    const float* aD1 = (const float*)d_in[4];
    const float* b1  = (const float*)d_in[5];
    const float* W2  = (const float*)d_in[6];
    const float* aS2 = (const float*)d_in[7];
    const float* aD2 = (const float*)d_in[8];
    const float* b2  = (const float*)d_in[9];

    char* ws = (char*)d_ws;
    size_t off = 0;
    auto alloc = [&](size_t bytes) { void* p = ws + off; off += (bytes + 255) & ~(size_t)255; return p; };

    unsigned short* h1 = (unsigned short*)alloc((size_t)NN * 128 * 2);  // bf16
    unsigned short* h2 = (unsigned short*)alloc((size_t)NN * 128 * 2);  // bf16
    float* as1 = (float*)alloc((size_t)NN * 8 * 4);
    float* ad1 = (float*)alloc((size_t)NN * 8 * 4);
    float* g2  = (float*)alloc((size_t)NN * 16 * 4);
    float* as2 = (float*)alloc((size_t)NN * 4);
    float* ad2 = (float*)alloc((size_t)NN * 4);
    unsigned int* packed = (unsigned int*)alloc((size_t)NBK * NCH * RCAP * 4);  // 7.4 MB
    int* cnts = (int*)alloc((size_t)NBK * NCH * 4);                              // 77 KB

    k_bin_gemm1<<<NCH + G1BLOCKS, 256, 0, stream>>>(ei, packed, cnts,
                                                    x, W1, aS1, aD1, h1, as1, ad1);
    k_final_agg1<<<NBK * 4, 256, 0, stream>>>(packed, cnts, as1, ad1, h1, b1, h2);
    k_gemm2<<<(NN + 63) / 64, 256, 0, stream>>>(h2, W2, aS2, aD2, g2, as2, ad2);
    k_final_agg2<<<NBK * 4, 256, 0, stream>>>(packed, cnts, as2, ad2, g2, b2,
                                              (float*)d_out);
}

// Round 12
// 195.485 us; speedup vs baseline: 1.2133x; 1.2133x over previous
//
#include <hip/hip_runtime.h>
#include <hip/hip_bf16.h>
#include <math.h>

#define NN 50000
#define NE 800000
#define NBK 196          // buckets = (NN+255)/256, bucket = dst>>8
#define CHUNK 8192
#define NCH ((NE + CHUNK - 1) / CHUNK)   // 98 chunks (= runs per bucket)
#define RCAP 96          // capacity per (bucket,chunk) run; mean 41.8, +8 sigma
#define APITCH 136       // padded bf16 row pitch for gemm1 A-tile
#define G1BLOCKS ((NN + 63) / 64)        // 782
#define SSP 5408         // per-bucket ssrc pitch (5120 edges + 256 self-loops + pad)

typedef short bf16x8 __attribute__((ext_vector_type(8)));
typedef float f32x4  __attribute__((ext_vector_type(4)));
typedef float f32x2  __attribute__((ext_vector_type(2)));

// ---------- bf16 helpers ----------
__device__ __forceinline__ unsigned short f2bf(float f) {
    union { float f; unsigned int i; } v; v.f = f;
    unsigned int x = v.i;
    unsigned int r = (x >> 16) & 1u;          // round-to-nearest-even
    x += 0x7fffu + r;
    return (unsigned short)(x >> 16);
}
__device__ __forceinline__ f32x2 up2(unsigned int u) {
    union { unsigned int i; float f; } x, y;
    x.i = u << 16; y.i = u & 0xffff0000u;
    return (f32x2){x.f, y.f};
}

// ---------- MERGED: single-pass edge binning (blocks 0..NCH-1) || layer-1 MFMA GEMM ----------
__global__ __launch_bounds__(256) void k_bin_gemm1(
    const int* __restrict__ ei,
    unsigned int* __restrict__ packed, int* __restrict__ cnts,
    const float* __restrict__ x, const float* __restrict__ W1,
    const float* __restrict__ aS, const float* __restrict__ aD,
    unsigned short* __restrict__ h1, float* __restrict__ as1,
    float* __restrict__ ad1)
{
    __shared__ union {
        int h[NBK];
        unsigned short alds[64 * APITCH];          // 34816 B
    } sm;
    int t = threadIdx.x;

    if (blockIdx.x < NCH) {
        // -------- bin: single pass, direct placement into fixed runs --------
        int* h = sm.h;
        if (t < NBK) h[t] = 0;
        __syncthreads();
        int cb = blockIdx.x * CHUNK;
#pragma unroll
        for (int k = 0; k < CHUNK / 256; k++) {
            int i = cb + k * 256 + t;
            if (i < NE) {
                int s = ei[i], d = ei[NE + i];
                int b = d >> 8;
                int r = atomicAdd(&h[b], 1);
                if (r < RCAP)
                    packed[((size_t)b * NCH + blockIdx.x) * RCAP + r] =
                        (unsigned int)s | ((unsigned int)(d & 255) << 16);
            }
        }
        __syncthreads();
        if (t < NBK) cnts[t * NCH + blockIdx.x] = (h[t] < RCAP) ? h[t] : RCAP;
        return;
    }

    // -------- gemm1 body (MFMA, self-swizzled W1 fragments) --------
    unsigned short* Alds = sm.alds;
    int w = t >> 6, l = t & 63;
    int rowbase = (blockIdx.x - NCH) * 64;

    {   // stage A: 64x128 fp32 -> bf16 LDS
        const float4* xg = (const float4*)(x + (size_t)rowbase * 128);
#pragma unroll
        for (int i = 0; i < 8; i++) {
            int idx = t + 256 * i;
            int r = idx >> 5, c = (idx & 31) * 4;
            float4 v = make_float4(0.f, 0.f, 0.f, 0.f);
            if (rowbase + r < NN) v = xg[idx];
            unsigned int p0 = (unsigned int)f2bf(v.x) | ((unsigned int)f2bf(v.y) << 16);
            unsigned int p1 = (unsigned int)f2bf(v.z) | ((unsigned int)f2bf(v.w) << 16);
            *(uint2*)&Alds[r * APITCH + c] = make_uint2(p0, p1);
        }
    }

    union BU { uint4 u; bf16x8 v; };
    BU b[2][4];
    {   // self-swizzle W1 -> B fragments (W1 is L2-resident across blocks)
        int n_lo = l & 15, k0b = (l >> 4) * 8;
#pragma unroll
        for (int j = 0; j < 2; j++) {
            int n = (2 * w + j) * 16 + n_lo;
#pragma unroll
            for (int kc = 0; kc < 4; kc++) {
                int k0 = kc * 32 + k0b;
                unsigned int p[4];
#pragma unroll
                for (int jj = 0; jj < 4; jj++) {
                    float v0 = W1[(k0 + 2 * jj) * 128 + n];
                    float v1 = W1[(k0 + 2 * jj + 1) * 128 + n];
                    p[jj] = (unsigned int)f2bf(v0) | ((unsigned int)f2bf(v1) << 16);
                }
                b[j][kc].u = make_uint4(p[0], p[1], p[2], p[3]);
            }
        }
    }
    __syncthreads();

    f32x4 acc[4][2];
#pragma unroll
    for (int mt = 0; mt < 4; mt++)
#pragma unroll
        for (int j = 0; j < 2; j++) acc[mt][j] = (f32x4){0.f, 0.f, 0.f, 0.f};

    int mrow = l & 15, quad = l >> 4;
#pragma unroll
    for (int kc = 0; kc < 4; kc++) {
#pragma unroll
        for (int mt = 0; mt < 4; mt++) {
            bf16x8 a = *(const bf16x8*)&Alds[(mt * 16 + mrow) * APITCH + kc * 32 + quad * 8];
            acc[mt][0] = __builtin_amdgcn_mfma_f32_16x16x32_bf16(a, b[0][kc].v, acc[mt][0], 0, 0, 0);
            acc[mt][1] = __builtin_amdgcn_mfma_f32_16x16x32_bf16(a, b[1][kc].v, acc[mt][1], 0, 0, 0);
        }
    }

#pragma unroll
    for (int j = 0; j < 2; j++) {
        int head = 2 * w + j;
        float aSv = aS[head * 16 + mrow];
        float aDv = aD[head * 16 + mrow];
#pragma unroll
        for (int mt = 0; mt < 4; mt++) {
#pragma unroll
            for (int reg = 0; reg < 4; reg++) {
                float s = acc[mt][j][reg] * aSv;
                float d = acc[mt][j][reg] * aDv;
                s += __shfl_xor(s, 1); s += __shfl_xor(s, 2);
                s += __shfl_xor(s, 4); s += __shfl_xor(s, 8);
                d += __shfl_xor(d, 1); d += __shfl_xor(d, 2);
                d += __shfl_xor(d, 4); d += __shfl_xor(d, 8);
                if (mrow == 0) {
                    int grow = rowbase + mt * 16 + quad * 4 + reg;
                    if (grow < NN) {
                        as1[grow * 8 + head] = s;
                        ad1[grow * 8 + head] = d;
                    }
                }
            }
        }
    }

    __syncthreads();   // A reads done; reuse Alds for C transpose
#pragma unroll
    for (int mt = 0; mt < 4; mt++)
#pragma unroll
        for (int j = 0; j < 2; j++) {
            int col = w * 32 + j * 16 + mrow;
#pragma unroll
            for (int reg = 0; reg < 4; reg++) {
                int r = mt * 16 + quad * 4 + reg;
                Alds[r * APITCH + col] = f2bf(acc[mt][j][reg]);
            }
        }
    __syncthreads();
    uint4* hg = (uint4*)h1;
#pragma unroll
    for (int i = 0; i < 4; i++) {
        int idx = t + 256 * i;
        int r = idx >> 4, ci = idx & 15;
        if (rowbase + r < NN)
            hg[(size_t)(rowbase + r) * 16 + ci] = *(const uint4*)&Alds[r * APITCH + ci * 8];
    }
}

// ---------- per-bucket finalize: concat fixed runs, rank by dst, append self-loops ----------
__global__ __launch_bounds__(256) void k_final(const unsigned int* __restrict__ packed,
                                               const int* __restrict__ cnts,
                                               int* __restrict__ deg,
                                               int* __restrict__ offs,
                                               int* __restrict__ ssrc) {
    __shared__ unsigned int pk[5120];
    __shared__ int osl[5376];
    __shared__ int rcnt[NCH], rpre[NCH + 1];
    __shared__ int cnt[256], pre[256], cur[256];
    int t = threadIdx.x, b = blockIdx.x;
    if (t < NCH) rcnt[t] = cnts[b * NCH + t];
    cnt[t] = 0;
    __syncthreads();
    if (t == 0) {
        int run = 0;
        for (int c = 0; c < NCH; c++) { rpre[c] = run; run += rcnt[c]; }
        rpre[NCH] = run;
    }
    __syncthreads();
    int n = rpre[NCH];
    int wv = t >> 6, ln = t & 63;
    for (int c = wv; c < NCH; c += 4) {
        int m = rcnt[c], base = rpre[c];
        const unsigned int* src = &packed[((size_t)b * NCH + c) * RCAP];
        for (int i = ln; i < m; i += 64) pk[base + i] = src[i];
    }
    __syncthreads();
    for (int i = t; i < n; i += 256) atomicAdd(&cnt[(pk[i] >> 16) & 255], 1);
    __syncthreads();
    int v = cnt[t];
    pre[t] = v;
    __syncthreads();
    for (int off = 1; off < 256; off <<= 1) {
        int u = (t >= off) ? pre[t - off] : 0;
        __syncthreads();
        pre[t] += u;
        __syncthreads();
    }
    int excl = pre[t] - v;
    int mybase = excl + t;               // +t self-slots of earlier nodes
    int dst = b * 256 + t;
    int start = b * SSP;
    if (dst < NN) {
        deg[dst] = v + 1;                // edges + self
        offs[dst] = start + mybase;
        osl[mybase + v] = dst;           // self-loop at segment end
    }
    cur[t] = mybase;
    __syncthreads();
    for (int i = t; i < n; i += 256) {
        unsigned int p = pk[i];
        int r = atomicAdd(&cur[(p >> 16) & 255], 1);
        osl[r] = (int)(p & 0xffffu);
    }
    __syncthreads();
    int nnodes = NN - b * 256; if (nnodes > 256) nnodes = 256;
    int n2 = n + nnodes;
    for (int i = t; i < n2; i += 256) ssrc[start + i] = osl[i];
}

// ---------- Layer 1 aggregation: lane = jg*8 + li, li == head, 32B/lane ----------
__global__ __launch_bounds__(256) void k_agg1(
    const int* __restrict__ offs, const int* __restrict__ deg,
    const int* __restrict__ ssrc,
    const float* __restrict__ as1, const float* __restrict__ ad1,
    const unsigned short* __restrict__ h1, const float* __restrict__ b1,
    unsigned short* __restrict__ h2)
{
    int wave = threadIdx.x >> 6;
    int lane = threadIdx.x & 63;
    int node = blockIdx.x * 4 + wave;
    if (node >= NN) return;
    int start = offs[node], cnt2 = deg[node];   // self-loop included

    int li = lane & 7, jg = lane >> 3;   // li = head, covers cols [li*16, li*16+16)
    float adv = ad1[node * 8 + li];

    const uint4* h1u4 = (const uint4*)h1;
    f32x2 acc[8];
#pragma unroll
    for (int i = 0; i < 8; i++) acc[i] = (f32x2){0.f, 0.f};
    float dsum = 0.f;

    for (int base = 0; base < cnt2; base += 32) {    // 4 x 8 edges in flight
#pragma unroll
        for (int u = 0; u < 4; u++) {
            int j = base + u * 8 + jg;
            if (j < cnt2) {
                int s = ssrc[start + j];
                float e = as1[s * 8 + li] + adv;
                e = (e > 0.f) ? e : 0.2f * e;
                float w = __expf(e);
                uint4 ha = h1u4[(size_t)s * 16 + 2 * li];
                uint4 hb = h1u4[(size_t)s * 16 + 2 * li + 1];
                f32x2 w2 = (f32x2){w, w};
                acc[0] += w2 * up2(ha.x); acc[1] += w2 * up2(ha.y);
                acc[2] += w2 * up2(ha.z); acc[3] += w2 * up2(ha.w);
                acc[4] += w2 * up2(hb.x); acc[5] += w2 * up2(hb.y);
                acc[6] += w2 * up2(hb.z); acc[7] += w2 * up2(hb.w);
                dsum += w;
            }
        }
    }

    // butterfly over the 8 jg groups (lanes with same li)
#pragma unroll
    for (int i = 0; i < 8; i++) {
        acc[i].x += __shfl_xor(acc[i].x, 8);  acc[i].y += __shfl_xor(acc[i].y, 8);
        acc[i].x += __shfl_xor(acc[i].x, 16); acc[i].y += __shfl_xor(acc[i].y, 16);
        acc[i].x += __shfl_xor(acc[i].x, 32); acc[i].y += __shfl_xor(acc[i].y, 32);
    }
    dsum += __shfl_xor(dsum, 8);
    dsum += __shfl_xor(dsum, 16);
    dsum += __shfl_xor(dsum, 32);

    if (jg == 0) {
        float inv = 1.0f / dsum;
        int c0 = li * 16;
        float v[16];
#pragma unroll
        for (int i = 0; i < 8; i++) {
            float v0 = acc[i].x * inv + b1[c0 + 2 * i];
            float v1 = acc[i].y * inv + b1[c0 + 2 * i + 1];
            v[2 * i]     = (v0 > 0.f) ? v0 : (__expf(v0) - 1.0f);   // ELU
            v[2 * i + 1] = (v1 > 0.f) ? v1 : (__expf(v1) - 1.0f);
        }
        uint4 o0, o1;
        o0.x = (unsigned int)f2bf(v[0])  | ((unsigned int)f2bf(v[1])  << 16);
        o0.y = (unsigned int)f2bf(v[2])  | ((unsigned int)f2bf(v[3])  << 16);
        o0.z = (unsigned int)f2bf(v[4])  | ((unsigned int)f2bf(v[5])  << 16);
        o0.w = (unsigned int)f2bf(v[6])  | ((unsigned int)f2bf(v[7])  << 16);
        o1.x = (unsigned int)f2bf(v[8])  | ((unsigned int)f2bf(v[9])  << 16);
        o1.y = (unsigned int)f2bf(v[10]) | ((unsigned int)f2bf(v[11]) << 16);
        o1.z = (unsigned int)f2bf(v[12]) | ((unsigned int)f2bf(v[13]) << 16);
        o1.w = (unsigned int)f2bf(v[14]) | ((unsigned int)f2bf(v[15]) << 16);
        ((uint4*)h2)[(size_t)node * 16 + 2 * li] = o0;
        ((uint4*)h2)[(size_t)node * 16 + 2 * li + 1] = o1;
    }
}

// ---------- Layer 2 GEMM via MFMA (self-swizzled W2), no LDS ----------
__global__ __launch_bounds__(256) void k_gemm2(
    const unsigned short* __restrict__ h2,   // [NN,128] bf16
    const float* __restrict__ W2,            // [128,16] fp32
    const float* __restrict__ aS2, const float* __restrict__ aD2,
    float* __restrict__ g2, float* __restrict__ as2, float* __restrict__ ad2)
{
    int t = threadIdx.x;
    int w = t >> 6, l = t & 63;
    int rowbase = blockIdx.x * 64 + w * 16;
    int arow = l & 15, quad = l >> 4;
    int row = rowbase + arow; if (row >= NN) row = NN - 1;   // clamp (discarded on store)

    union BU { uint4 u; bf16x8 v; };
    BU bfr[4];
    {
        int n = l & 15, k0b = (l >> 4) * 8;
#pragma unroll
        for (int kc = 0; kc < 4; kc++) {
            int k0 = kc * 32 + k0b;
            unsigned int p[4];
#pragma unroll
            for (int jj = 0; jj < 4; jj++) {
                float v0 = W2[(k0 + 2 * jj) * 16 + n];
                float v1 = W2[(k0 + 2 * jj + 1) * 16 + n];
                p[jj] = (unsigned int)f2bf(v0) | ((unsigned int)f2bf(v1) << 16);
            }
            bfr[kc].u = make_uint4(p[0], p[1], p[2], p[3]);
        }
    }

    f32x4 acc = (f32x4){0.f, 0.f, 0.f, 0.f};
#pragma unroll
    for (int kc = 0; kc < 4; kc++) {
        bf16x8 a = *(const bf16x8*)&h2[(size_t)row * 128 + kc * 32 + quad * 8];
        acc = __builtin_amdgcn_mfma_f32_16x16x32_bf16(a, bfr[kc].v, acc, 0, 0, 0);
    }

    int col = l & 15;
    float aSv = aS2[col], aDv = aD2[col];
#pragma unroll
    for (int reg = 0; reg < 4; reg++) {
        int grow = rowbase + quad * 4 + reg;
        if (grow < NN) g2[(size_t)grow * 16 + col] = acc[reg];
        float s = acc[reg] * aSv;
        float d = acc[reg] * aDv;
        s += __shfl_xor(s, 1); s += __shfl_xor(s, 2);
        s += __shfl_xor(s, 4); s += __shfl_xor(s, 8);
        d += __shfl_xor(d, 1); d += __shfl_xor(d, 2);
        d += __shfl_xor(d, 4); d += __shfl_xor(d, 8);
        if (col == 0 && grow < NN) { as2[grow] = s; ad2[grow] = d; }
    }
}

// ---------- Layer 2 aggregation: 32 edges in flight ----------
__global__ __launch_bounds__(256) void k_agg2(
    const int* __restrict__ offs, const int* __restrict__ deg,
    const int* __restrict__ ssrc,
    const float* __restrict__ as2, const float* __restrict__ ad2,
    const float* __restrict__ g2, const float* __restrict__ b2,
    float* __restrict__ out)
{
    int wave = threadIdx.x >> 6;
    int lane = threadIdx.x & 63;
    int node = blockIdx.x * 4 + wave;
    if (node >= NN) return;
    int start = offs[node], cnt2 = deg[node];   // self-loop included
    float adv = ad2[node];

    int li4 = lane & 3, jg = lane >> 2;
    const float4* g2f4 = (const float4*)g2;

    float a0 = 0.f, a1 = 0.f, a2 = 0.f, a3 = 0.f, dsum = 0.f;
    for (int base = 0; base < cnt2; base += 32) {
#pragma unroll
        for (int u = 0; u < 2; u++) {
            int j = base + u * 16 + jg;
            if (j < cnt2) {
                int s = ssrc[start + j];
                float e = as2[s] + adv;
                e = (e > 0.f) ? e : 0.2f * e;
                float w = __expf(e);
                float4 g = g2f4[(size_t)s * 4 + li4];
                a0 += w * g.x; a1 += w * g.y; a2 += w * g.z; a3 += w * g.w;
                if (li4 == 0) dsum += w;
            }
        }
    }
#pragma unroll
    for (int m = 4; m < 64; m <<= 1) {
        a0 += __shfl_xor(a0, m); a1 += __shfl_xor(a1, m);
        a2 += __shfl_xor(a2, m); a3 += __shfl_xor(a3, m);
        dsum += __shfl_xor(dsum, m);
    }
    dsum += __shfl_xor(dsum, 1);
    dsum += __shfl_xor(dsum, 2);   // broadcast denom to all li4

    if (jg == 0) {
        float inv = 1.0f / dsum;
        const float4* b2f4 = (const float4*)b2;
        float4 bb = b2f4[li4];
        float4 o = make_float4(a0 * inv + bb.x, a1 * inv + bb.y,
                               a2 * inv + bb.z, a3 * inv + bb.w);
        ((float4*)out)[(size_t)node * 4 + li4] = o;
    }
}

// ---------- launch ----------
extern "C" void kernel_launch(void* const* d_in, const int* in_sizes, int n_in,
                              void* d_out, int out_size, void* d_ws, size_t ws_size,
                              hipStream_t stream) {
    const float* x   = (const float*)d_in[0];
    const int*   ei  = (const int*)d_in[1];
    const float* W1  = (const float*)d_in[2];
    const float* aS1 = (const float*)d_in[3];
    const float* aD1 = (const float*)d_in[4];
    const float* b1  = (const float*)d_in[5];
    const float* W2  = (const float*)d_in[6];
    const float* aS2 = (const float*)d_in[7];
    const float* aD2 = (const float*)d_in[8];
    const float* b2  = (const float*)d_in[9];

    char* ws = (char*)d_ws;
    size_t off = 0;
    auto alloc = [&](size_t bytes) { void* p = ws + off; off += (bytes + 255) & ~(size_t)255; return p; };

    unsigned short* h1 = (unsigned short*)alloc((size_t)NN * 128 * 2);  // bf16
    unsigned short* h2 = (unsigned short*)alloc((size_t)NN * 128 * 2);  // bf16
    float* as1 = (float*)alloc((size_t)NN * 8 * 4);
    float* ad1 = (float*)alloc((size_t)NN * 8 * 4);
    float* g2  = (float*)alloc((size_t)NN * 16 * 4);
    float* as2 = (float*)alloc((size_t)NN * 4);
    float* ad2 = (float*)alloc((size_t)NN * 4);
    int* deg    = (int*)alloc((size_t)NN * 4);
    int* offs   = (int*)alloc((size_t)NN * 4);
    int* ssrc   = (int*)alloc((size_t)NBK * SSP * 4);
    unsigned int* packed = (unsigned int*)alloc((size_t)NBK * NCH * RCAP * 4);  // 7.4 MB
    int* cnts = (int*)alloc((size_t)NBK * NCH * 4);                              // 77 KB

    k_bin_gemm1<<<NCH + G1BLOCKS, 256, 0, stream>>>(ei, packed, cnts,
                                                    x, W1, aS1, aD1, h1, as1, ad1);
    k_final<<<NBK, 256, 0, stream>>>(packed, cnts, deg, offs, ssrc);
    k_agg1<<<(NN + 3) / 4, 256, 0, stream>>>(offs, deg, ssrc, as1, ad1, h1, b1, h2);
    k_gemm2<<<(NN + 63) / 64, 256, 0, stream>>>(h2, W2, aS2, aD2, g2, as2, ad2);
    k_agg2<<<(NN + 3) / 4, 256, 0, stream>>>(offs, deg, ssrc, as2, ad2, g2, b2,
                                             (float*)d_out);
}

// Round 13
// 187.055 us; speedup vs baseline: 1.2680x; 1.0451x over previous
//
#include <hip/hip_runtime.h>
#include <hip/hip_bf16.h>
#include <math.h>

#define NN 50000
#define NE 800000
#define NBK 196          // buckets = (NN+255)/256, bucket = dst>>8
#define BCAP 5120        // fixed bucket capacity (edges + 256 self-loops fits)
#define CHUNK 8192
#define NCH ((NE + CHUNK - 1) / CHUNK)   // 98
#define APITCH 136       // padded bf16 row pitch for gemm1 A-tile
#define G1BLOCKS ((NN + 63) / 64)        // 782

typedef short bf16x8 __attribute__((ext_vector_type(8)));
typedef float f32x4  __attribute__((ext_vector_type(4)));
typedef float f32x2  __attribute__((ext_vector_type(2)));

// ---------- bf16 helpers ----------
__device__ __forceinline__ unsigned short f2bf(float f) {
    union { float f; unsigned int i; } v; v.f = f;
    unsigned int x = v.i;
    unsigned int r = (x >> 16) & 1u;          // round-to-nearest-even
    x += 0x7fffu + r;
    return (unsigned short)(x >> 16);
}
__device__ __forceinline__ f32x2 up2(unsigned int u) {
    union { unsigned int i; float f; } x, y;
    x.i = u << 16; y.i = u & 0xffff0000u;
    return (f32x2){x.f, y.f};
}

// ---------- W1/W2 swizzle + gcur zero (runs first; 9 blocks) ----------
__global__ __launch_bounds__(256) void k_swizw(const float* __restrict__ W1,
                                               const float* __restrict__ W2,
                                               uint4* __restrict__ W1s,
                                               uint4* __restrict__ W2s,
                                               int* __restrict__ gcur) {
    int t = threadIdx.x;
    if (blockIdx.x == 8) {
        if (t < NBK) gcur[t] = 0;
        // W2 -> B fragments (bf16): frag f = kc*64 + l, B[k=kc*32+(l>>4)*8+j][n=l&15]
        int kc = t >> 6, l = t & 63;
        int n = l & 15, k0 = kc * 32 + (l >> 4) * 8;
        unsigned int p[4];
#pragma unroll
        for (int jj = 0; jj < 4; jj++) {
            float v0 = W2[(k0 + 2 * jj) * 16 + n];
            float v1 = W2[(k0 + 2 * jj + 1) * 16 + n];
            p[jj] = (unsigned int)f2bf(v0) | ((unsigned int)f2bf(v1) << 16);
        }
        W2s[t] = make_uint4(p[0], p[1], p[2], p[3]);
        return;
    }
    int f = blockIdx.x * 256 + t;             // [0,2048)
    int nt = f >> 8, kc = (f >> 6) & 3, l = f & 63;
    int n  = nt * 16 + (l & 15);
    int k0 = kc * 32 + (l >> 4) * 8;
    unsigned int p[4];
#pragma unroll
    for (int jj = 0; jj < 4; jj++) {
        float v0 = W1[(k0 + 2 * jj) * 128 + n];
        float v1 = W1[(k0 + 2 * jj + 1) * 128 + n];
        p[jj] = (unsigned int)f2bf(v0) | ((unsigned int)f2bf(v1) << 16);
    }
    W1s[f] = make_uint4(p[0], p[1], p[2], p[3]);
}

// ---------- MERGED: edge binning (blocks 0..NCH-1)  ||  layer-1 MFMA GEMM ----------
__global__ __launch_bounds__(256) void k_bin_gemm1(
    const int* __restrict__ ei, int* __restrict__ gcur,
    unsigned int* __restrict__ packed,
    const float* __restrict__ x, const uint4* __restrict__ W1s,
    const float* __restrict__ aS, const float* __restrict__ aD,
    unsigned short* __restrict__ h1, float* __restrict__ as1,
    float* __restrict__ ad1)
{
    __shared__ union {
        struct { int h[NBK]; int bas[NBK]; } bin;
        unsigned short alds[64 * APITCH];          // 34816 B
    } sm;
    int t = threadIdx.x;

    if (blockIdx.x < NCH) {
        int* h = sm.bin.h;
        int* bas = sm.bin.bas;
        if (t < NBK) h[t] = 0;
        __syncthreads();
        int cb = blockIdx.x * CHUNK;
#pragma unroll
        for (int k = 0; k < CHUNK / 256; k++) {
            int i = cb + k * 256 + t;
            if (i < NE) atomicAdd(&h[ei[NE + i] >> 8], 1);
        }
        __syncthreads();
        if (t < NBK) {
            int c = h[t];
            bas[t] = c ? (t * BCAP + atomicAdd(&gcur[t], c)) : 0;
            h[t] = 0;
        }
        __syncthreads();
#pragma unroll
        for (int k = 0; k < CHUNK / 256; k++) {
            int i = cb + k * 256 + t;
            if (i < NE) {
                int s = ei[i], d = ei[NE + i];
                int b = d >> 8;
                int r = atomicAdd(&h[b], 1);
                packed[bas[b] + r] = (unsigned int)s | ((unsigned int)(d & 255) << 16);
            }
        }
        return;
    }

    // ---------------- gemm1 body ----------------
    unsigned short* Alds = sm.alds;
    int w = t >> 6, l = t & 63;
    int rowbase = (blockIdx.x - NCH) * 64;

    {
        const float4* xg = (const float4*)(x + (size_t)rowbase * 128);
#pragma unroll
        for (int i = 0; i < 8; i++) {
            int idx = t + 256 * i;             // float4 id [0,2048)
            int r = idx >> 5, c = (idx & 31) * 4;
            float4 v = make_float4(0.f, 0.f, 0.f, 0.f);
            if (rowbase + r < NN) v = xg[idx];
            unsigned int p0 = (unsigned int)f2bf(v.x) | ((unsigned int)f2bf(v.y) << 16);
            unsigned int p1 = (unsigned int)f2bf(v.z) | ((unsigned int)f2bf(v.w) << 16);
            *(uint2*)&Alds[r * APITCH + c] = make_uint2(p0, p1);
        }
    }

    union BU { uint4 u; bf16x8 v; };
    BU b[2][4];
#pragma unroll
    for (int j = 0; j < 2; j++) {
        int nt = 2 * w + j;
#pragma unroll
        for (int kc = 0; kc < 4; kc++)
            b[j][kc].u = W1s[(nt * 4 + kc) * 64 + l];
    }
    __syncthreads();

    f32x4 acc[4][2];
#pragma unroll
    for (int mt = 0; mt < 4; mt++)
#pragma unroll
        for (int j = 0; j < 2; j++) acc[mt][j] = (f32x4){0.f, 0.f, 0.f, 0.f};

    int mrow = l & 15, quad = l >> 4;
#pragma unroll
    for (int kc = 0; kc < 4; kc++) {
#pragma unroll
        for (int mt = 0; mt < 4; mt++) {
            bf16x8 a = *(const bf16x8*)&Alds[(mt * 16 + mrow) * APITCH + kc * 32 + quad * 8];
            acc[mt][0] = __builtin_amdgcn_mfma_f32_16x16x32_bf16(a, b[0][kc].v, acc[mt][0], 0, 0, 0);
            acc[mt][1] = __builtin_amdgcn_mfma_f32_16x16x32_bf16(a, b[1][kc].v, acc[mt][1], 0, 0, 0);
        }
    }

#pragma unroll
    for (int j = 0; j < 2; j++) {
        int head = 2 * w + j;
        float aSv = aS[head * 16 + mrow];
        float aDv = aD[head * 16 + mrow];
#pragma unroll
        for (int mt = 0; mt < 4; mt++) {
#pragma unroll
            for (int reg = 0; reg < 4; reg++) {
                float s = acc[mt][j][reg] * aSv;
                float d = acc[mt][j][reg] * aDv;
                s += __shfl_xor(s, 1); s += __shfl_xor(s, 2);
                s += __shfl_xor(s, 4); s += __shfl_xor(s, 8);
                d += __shfl_xor(d, 1); d += __shfl_xor(d, 2);
                d += __shfl_xor(d, 4); d += __shfl_xor(d, 8);
                if (mrow == 0) {
                    int grow = rowbase + mt * 16 + quad * 4 + reg;
                    if (grow < NN) {
                        as1[grow * 8 + head] = s;
                        ad1[grow * 8 + head] = d;
                    }
                }
            }
        }
    }

    __syncthreads();   // A reads done; reuse Alds for C transpose
#pragma unroll
    for (int mt = 0; mt < 4; mt++)
#pragma unroll
        for (int j = 0; j < 2; j++) {
            int col = w * 32 + j * 16 + mrow;
#pragma unroll
            for (int reg = 0; reg < 4; reg++) {
                int r = mt * 16 + quad * 4 + reg;
                Alds[r * APITCH + col] = f2bf(acc[mt][j][reg]);
            }
        }
    __syncthreads();
    uint4* hg = (uint4*)h1;   // 16 uint4 per 128-col row
#pragma unroll
    for (int i = 0; i < 4; i++) {
        int idx = t + 256 * i;           // uint4 id [0,1024)
        int r = idx >> 4, ci = idx & 15;
        if (rowbase + r < NN)
            hg[(size_t)(rowbase + r) * 16 + ci] = *(const uint4*)&Alds[r * APITCH + ci * 8];
    }
}

// ---------- per-bucket finalize: rank by dst, APPEND SELF-LOOP per node ----------
__global__ __launch_bounds__(256) void k_final(const unsigned int* __restrict__ packed,
                                               const int* __restrict__ gcur,
                                               int* __restrict__ deg,
                                               int* __restrict__ offs,
                                               int* __restrict__ ssrc) {
    __shared__ unsigned int pk[BCAP];
    __shared__ int osl[BCAP];
    __shared__ int cnt[256], pre[256], cur[256];
    int t = threadIdx.x, b = blockIdx.x;
    int start = b * BCAP;
    int n = gcur[b];
    int nnodes = NN - b * 256; if (nnodes > 256) nnodes = 256;
    for (int i = t; i < n; i += 256) pk[i] = packed[start + i];
    cnt[t] = 0;
    __syncthreads();
    for (int i = t; i < n; i += 256) atomicAdd(&cnt[(pk[i] >> 16) & 255], 1);
    __syncthreads();
    int v = cnt[t];
    pre[t] = v;
    __syncthreads();
    for (int off = 1; off < 256; off <<= 1) {
        int u = (t >= off) ? pre[t - off] : 0;
        __syncthreads();
        pre[t] += u;
        __syncthreads();
    }
    int excl = pre[t] - v;
    int mybase = excl + t;               // +t self-slots of earlier nodes
    int dst = b * 256 + t;
    if (dst < NN) {
        deg[dst] = v + 1;                // cnt2: edges + self
        offs[dst] = start + mybase;
        osl[mybase + v] = dst;           // self-loop at segment end
    }
    cur[t] = mybase;
    __syncthreads();
    for (int i = t; i < n; i += 256) {
        unsigned int p = pk[i];
        int r = atomicAdd(&cur[(p >> 16) & 255], 1);
        osl[r] = (int)(p & 0xffffu);
    }
    __syncthreads();
    int n2 = n + nnodes;
    for (int i = t; i < n2; i += 256) ssrc[start + i] = osl[i];
}

// ---------- Layer 1 aggregation: lane = jg*8 + li, li == head, 32B/lane ----------
__global__ __launch_bounds__(256) void k_agg1(
    const int* __restrict__ offs, const int* __restrict__ deg,
    const int* __restrict__ ssrc,
    const float* __restrict__ as1, const float* __restrict__ ad1,
    const unsigned short* __restrict__ h1, const float* __restrict__ b1,
    unsigned short* __restrict__ h2)
{
    int wave = threadIdx.x >> 6;
    int lane = threadIdx.x & 63;
    int node = blockIdx.x * 4 + wave;
    if (node >= NN) return;
    int start = offs[node], cnt2 = deg[node];   // self-loop included

    int li = lane & 7, jg = lane >> 3;   // li = head, covers cols [li*16, li*16+16)
    float adv = ad1[node * 8 + li];

    const uint4* h1u4 = (const uint4*)h1;
    f32x2 acc[8];
#pragma unroll
    for (int i = 0; i < 8; i++) acc[i] = (f32x2){0.f, 0.f};
    float dsum = 0.f;

    for (int base = 0; base < cnt2; base += 32) {    // 4 x 8 edges in flight
#pragma unroll
        for (int u = 0; u < 4; u++) {
            int j = base + u * 8 + jg;
            if (j < cnt2) {
                int s = ssrc[start + j];
                float e = as1[s * 8 + li] + adv;
                e = (e > 0.f) ? e : 0.2f * e;
                float w = __expf(e);
                uint4 ha = h1u4[(size_t)s * 16 + 2 * li];
                uint4 hb = h1u4[(size_t)s * 16 + 2 * li + 1];
                f32x2 w2 = (f32x2){w, w};
                acc[0] += w2 * up2(ha.x); acc[1] += w2 * up2(ha.y);
                acc[2] += w2 * up2(ha.z); acc[3] += w2 * up2(ha.w);
                acc[4] += w2 * up2(hb.x); acc[5] += w2 * up2(hb.y);
                acc[6] += w2 * up2(hb.z); acc[7] += w2 * up2(hb.w);
                dsum += w;
            }
        }
    }

    // butterfly over the 8 jg groups (lanes with same li)
#pragma unroll
    for (int i = 0; i < 8; i++) {
        acc[i].x += __shfl_xor(acc[i].x, 8);  acc[i].y += __shfl_xor(acc[i].y, 8);
        acc[i].x += __shfl_xor(acc[i].x, 16); acc[i].y += __shfl_xor(acc[i].y, 16);
        acc[i].x += __shfl_xor(acc[i].x, 32); acc[i].y += __shfl_xor(acc[i].y, 32);
    }
    dsum += __shfl_xor(dsum, 8);
    dsum += __shfl_xor(dsum, 16);
    dsum += __shfl_xor(dsum, 32);

    if (jg == 0) {
        float inv = 1.0f / dsum;
        int c0 = li * 16;
        float v[16];
#pragma unroll
        for (int i = 0; i < 8; i++) {
            float v0 = acc[i].x * inv + b1[c0 + 2 * i];
            float v1 = acc[i].y * inv + b1[c0 + 2 * i + 1];
            v[2 * i]     = (v0 > 0.f) ? v0 : (__expf(v0) - 1.0f);   // ELU
            v[2 * i + 1] = (v1 > 0.f) ? v1 : (__expf(v1) - 1.0f);
        }
        uint4 o0, o1;
        o0.x = (unsigned int)f2bf(v[0])  | ((unsigned int)f2bf(v[1])  << 16);
        o0.y = (unsigned int)f2bf(v[2])  | ((unsigned int)f2bf(v[3])  << 16);
        o0.z = (unsigned int)f2bf(v[4])  | ((unsigned int)f2bf(v[5])  << 16);
        o0.w = (unsigned int)f2bf(v[6])  | ((unsigned int)f2bf(v[7])  << 16);
        o1.x = (unsigned int)f2bf(v[8])  | ((unsigned int)f2bf(v[9])  << 16);
        o1.y = (unsigned int)f2bf(v[10]) | ((unsigned int)f2bf(v[11]) << 16);
        o1.z = (unsigned int)f2bf(v[12]) | ((unsigned int)f2bf(v[13]) << 16);
        o1.w = (unsigned int)f2bf(v[14]) | ((unsigned int)f2bf(v[15]) << 16);
        ((uint4*)h2)[(size_t)node * 16 + 2 * li] = o0;
        ((uint4*)h2)[(size_t)node * 16 + 2 * li + 1] = o1;
    }
}

// ---------- Layer 2 GEMM via MFMA: g2 = h2 @ W2 (bf16), no LDS ----------
__global__ __launch_bounds__(256) void k_gemm2(
    const unsigned short* __restrict__ h2,   // [NN,128] bf16
    const uint4* __restrict__ W2s,           // 256 bf16 B-fragments
    const float* __restrict__ aS2, const float* __restrict__ aD2,
    float* __restrict__ g2, float* __restrict__ as2, float* __restrict__ ad2)
{
    int t = threadIdx.x;
    int w = t >> 6, l = t & 63;
    int rowbase = blockIdx.x * 64 + w * 16;
    int arow = l & 15, quad = l >> 4;
    int row = rowbase + arow; if (row >= NN) row = NN - 1;   // clamp (discarded on store)

    union BU { uint4 u; bf16x8 v; };
    f32x4 acc = (f32x4){0.f, 0.f, 0.f, 0.f};
#pragma unroll
    for (int kc = 0; kc < 4; kc++) {
        bf16x8 a = *(const bf16x8*)&h2[(size_t)row * 128 + kc * 32 + quad * 8];
        BU b; b.u = W2s[kc * 64 + l];
        acc = __builtin_amdgcn_mfma_f32_16x16x32_bf16(a, b.v, acc, 0, 0, 0);
    }

    int col = l & 15;
    float aSv = aS2[col], aDv = aD2[col];
#pragma unroll
    for (int reg = 0; reg < 4; reg++) {
        int grow = rowbase + quad * 4 + reg;
        if (grow < NN) g2[(size_t)grow * 16 + col] = acc[reg];
        float s = acc[reg] * aSv;
        float d = acc[reg] * aDv;
        s += __shfl_xor(s, 1); s += __shfl_xor(s, 2);
        s += __shfl_xor(s, 4); s += __shfl_xor(s, 8);
        d += __shfl_xor(d, 1); d += __shfl_xor(d, 2);
        d += __shfl_xor(d, 4); d += __shfl_xor(d, 8);
        if (col == 0 && grow < NN) { as2[grow] = s; ad2[grow] = d; }
    }
}

// ---------- Layer 2 aggregation: 32 edges in flight ----------
__global__ __launch_bounds__(256) void k_agg2(
    const int* __restrict__ offs, const int* __restrict__ deg,
    const int* __restrict__ ssrc,
    const float* __restrict__ as2, const float* __restrict__ ad2,
    const float* __restrict__ g2, const float* __restrict__ b2,
    float* __restrict__ out)
{
    int wave = threadIdx.x >> 6;
    int lane = threadIdx.x & 63;
    int node = blockIdx.x * 4 + wave;
    if (node >= NN) return;
    int start = offs[node], cnt2 = deg[node];   // self-loop included
    float adv = ad2[node];

    int li4 = lane & 3, jg = lane >> 2;
    const float4* g2f4 = (const float4*)g2;

    float a0 = 0.f, a1 = 0.f, a2 = 0.f, a3 = 0.f, dsum = 0.f;
    for (int base = 0; base < cnt2; base += 32) {
#pragma unroll
        for (int u = 0; u < 2; u++) {
            int j = base + u * 16 + jg;
            if (j < cnt2) {
                int s = ssrc[start + j];
                float e = as2[s] + adv;
                e = (e > 0.f) ? e : 0.2f * e;
                float w = __expf(e);
                float4 g = g2f4[(size_t)s * 4 + li4];
                a0 += w * g.x; a1 += w * g.y; a2 += w * g.z; a3 += w * g.w;
                if (li4 == 0) dsum += w;
            }
        }
    }
#pragma unroll
    for (int m = 4; m < 64; m <<= 1) {
        a0 += __shfl_xor(a0, m); a1 += __shfl_xor(a1, m);
        a2 += __shfl_xor(a2, m); a3 += __shfl_xor(a3, m);
        dsum += __shfl_xor(dsum, m);
    }
    dsum += __shfl_xor(dsum, 1);
    dsum += __shfl_xor(dsum, 2);   // broadcast denom to all li4

    if (jg == 0) {
        float inv = 1.0f / dsum;
        const float4* b2f4 = (const float4*)b2;
        float4 bb = b2f4[li4];
        float4 o = make_float4(a0 * inv + bb.x, a1 * inv + bb.y,
                               a2 * inv + bb.z, a3 * inv + bb.w);
        ((float4*)out)[(size_t)node * 4 + li4] = o;
    }
}

// ---------- launch ----------
extern "C" void kernel_launch(void* const* d_in, const int* in_sizes, int n_in,
                              void* d_out, int out_size, void* d_ws, size_t ws_size,
                              hipStream_t stream) {
    const float* x   = (const float*)d_in[0];
    const int*   ei  = (const int*)d_in[1];
    const float* W1  = (const float*)d_in[2];
    const float* aS1 = (const float*)d_in[3];
    const float* aD1 = (const float*)d_in[4];
    const float* b1  = (const float*)d_in[5];
    const float* W2  = (const float*)d_in[6];
    const float* aS2 = (const float*)d_in[7];
    const float* aD2 = (const float*)d_in[8];
    const float* b2  = (const float*)d_in[9];

    char* ws = (char*)d_ws;
    size_t off = 0;
    auto alloc = [&](size_t bytes) { void* p = ws + off; off += (bytes + 255) & ~(size_t)255; return p; };

    unsigned short* h1 = (unsigned short*)alloc((size_t)NN * 128 * 2);  // bf16
    unsigned short* h2 = (unsigned short*)alloc((size_t)NN * 128 * 2);  // bf16
    float* as1 = (float*)alloc((size_t)NN * 8 * 4);
    float* ad1 = (float*)alloc((size_t)NN * 8 * 4);
    float* g2  = (float*)alloc((size_t)NN * 16 * 4);
    float* as2 = (float*)alloc((size_t)NN * 4);
    float* ad2 = (float*)alloc((size_t)NN * 4);
    int* deg    = (int*)alloc((size_t)NN * 4);
    int* offs   = (int*)alloc((size_t)NN * 4);
    int* ssrc   = (int*)alloc((size_t)NBK * BCAP * 4);
    unsigned int* packed = (unsigned int*)alloc((size_t)NBK * BCAP * 4);
    int* gcur   = (int*)alloc((size_t)NBK * 4);
    uint4* W1s  = (uint4*)alloc((size_t)2048 * 16);   // swizzled bf16 W1
    uint4* W2s  = (uint4*)alloc((size_t)256 * 16);    // swizzled bf16 W2

    k_swizw<<<9, 256, 0, stream>>>(W1, W2, W1s, W2s, gcur);
    k_bin_gemm1<<<NCH + G1BLOCKS, 256, 0, stream>>>(ei, gcur, packed,
                                                    x, W1s, aS1, aD1, h1, as1, ad1);
    k_final<<<NBK, 256, 0, stream>>>(packed, gcur, deg, offs, ssrc);
    k_agg1<<<(NN + 3) / 4, 256, 0, stream>>>(offs, deg, ssrc, as1, ad1, h1, b1, h2);
    k_gemm2<<<(NN + 63) / 64, 256, 0, stream>>>(h2, W2s, aS2, aD2, g2, as2, ad2);
    k_agg2<<<(NN + 3) / 4, 256, 0, stream>>>(offs, deg, ssrc, as2, ad2, g2, b2,
                                             (float*)d_out);
}